// Round 5
// baseline (1879.080 us; speedup 1.0000x reference)
//
#include <hip/hip_runtime.h>
#include <math.h>

#define Bb 256
#define Tt 1024
#define Ll 128
#define SHIFT 16.0f

// ---------------- exp(trans) transpose precompute ----------------
// expT[j*128 + i] = exp(trans[i*128 + j])
__global__ __launch_bounds__(256) void crf_expT_kernel(
    const float* __restrict__ trans, float* __restrict__ expT)
{
    int idx = blockIdx.x * 256 + threadIdx.x;   // idx = j*128 + i
    if (idx < Ll * Ll) {
        int jj = idx >> 7;
        int ii = idx & (Ll - 1);
        expT[idx] = __expf(trans[ii * Ll + jj]);
    }
}

// ---------------- numerator kernel ----------------
__global__ __launch_bounds__(256) void crf_num_kernel(
    const float* __restrict__ h, const int* __restrict__ labels,
    const float* __restrict__ mask, const float* __restrict__ trans,
    const float* __restrict__ start_trans, const float* __restrict__ end_trans,
    float* __restrict__ num_out)
{
    const int b = blockIdx.x;
    const int tid = threadIdx.x;
    const int* lab = labels + b * Tt;
    const float* mk = mask + b * Tt;
    const float* hb = h + (size_t)b * Tt * Ll;

    float acc = 0.f;
    float msum = 0.f;
    for (int t = tid; t < Tt; t += 256) {
        int lt = lab[t];
        float mt = mk[t];
        msum += mt;
        if (t < Tt - 1) {
            int lt1 = lab[t + 1];
            acc += hb[t * Ll + lt] * mt + trans[lt * Ll + lt1] * mk[t + 1];
        }
    }
    for (int off = 32; off; off >>= 1) {
        acc  += __shfl_down(acc, off, 64);
        msum += __shfl_down(msum, off, 64);
    }
    __shared__ float racc[4], rmsum[4];
    const int wave = tid >> 6;
    if ((tid & 63) == 0) { racc[wave] = acc; rmsum[wave] = msum; }
    __syncthreads();
    if (tid == 0) {
        float a = racc[0] + racc[1] + racc[2] + racc[3];
        float m = rmsum[0] + rmsum[1] + rmsum[2] + rmsum[3];
        int last_idx = (int)(m + 0.5f) - 1;
        if (last_idx < 0) last_idx = 0;
        if (last_idx > Tt - 1) last_idx = Tt - 1;
        int last_lab = lab[last_idx];
        float num = a + start_trans[lab[0]];
        num += hb[(Tt - 1) * Ll + last_lab] * mk[Tt - 1];
        num += end_trans[last_lab];
        num_out[b] = num;
    }
}

// ---------------- denominator (forward scan) kernel ----------------
// ONE WAVE per batch: 256 blocks x 64 threads. ZERO barriers in the scan loop
// (rounds 1-4 showed ~1700 cy/step; __syncthreads drains vmcnt(0), serializing
// the h prefetch into every step). Lane l owns columns jA=l, jB=l+64 with the
// FULL i-range: exp(trans) fragment = 64 float4 (256 f32, overflows into the
// AGPR half of the unified file under waves_per_eu(1,1) -- reg-to-reg, not
// scratch). p exchanged through LDS with broadcast same-address ds_read_b128
// (conflict-free) + s_waitcnt lgkmcnt(0) only; wave-lockstep makes cross-lane
// LDS visibility safe without s_barrier. Shift = lane0 score (readlane) + 16,
// applied and un-applied with the SAME value -> algebraically exact.
// h prefetched 3 steps deep in registers; loads stay in flight across steps.
__global__ __launch_bounds__(64)
__attribute__((amdgpu_waves_per_eu(1, 1)))
void crf_den_kernel(
    const float* __restrict__ h, const float* __restrict__ mask,
    const float* __restrict__ expT, const float* __restrict__ start_trans,
    const float* __restrict__ end_trans, const float* __restrict__ num_in,
    float* __restrict__ out)
{
    __shared__ float p_lds[Ll];
    __shared__ float mk_lds[Tt];

    const int b = blockIdx.x;
    const int lane = threadIdx.x;          // 0..63
    const int jA = lane;
    const int jB = lane + 64;
    const float* hb = h + (size_t)b * Tt * Ll;

    // stage mask row (same-wave visibility via lgkmcnt, no barrier needed)
    for (int t = lane; t < Tt; t += 64) mk_lds[t] = mask[b * Tt + t];

    // exp(trans) fragments: 2 full columns = 64 float4 regs, static indices only
    float4 eA[32], eB[32];
    {
        const float4* epA = (const float4*)(expT + jA * Ll);
        const float4* epB = (const float4*)(expT + jB * Ll);
        #pragma unroll
        for (int k = 0; k < 32; ++k) { eA[k] = epA[k]; eB[k] = epB[k]; }
    }

    // bootstrap t = 0
    float scoreA = start_trans[jA] + hb[jA];
    float scoreB = start_trans[jB] + hb[jB];
    float S = __shfl(scoreA, 0, 64) + SHIFT;   // lane0 == column 0
    p_lds[jA] = __expf(scoreA - S);
    p_lds[jB] = __expf(scoreB - S);

    // h pipeline, 3 deep
    float hA0 = hb[1 * Ll + jA], hB0 = hb[1 * Ll + jB];
    float hA1 = hb[2 * Ll + jA], hB1 = hb[2 * Ll + jB];
    float hA2 = hb[3 * Ll + jA], hB2 = hb[3 * Ll + jB];

    #pragma unroll 1
    for (int t = 1; t < Tt; ++t) {
        // wait for p writes (and first iter: mask staging); LDS only — the
        // h-prefetch global loads remain in flight (no vmcnt drain!)
        asm volatile("s_waitcnt lgkmcnt(0)" ::: "memory");

        const float4* pld = (const float4*)p_lds;
        float a0 = 0.f, a1 = 0.f, a2 = 0.f, a3 = 0.f;
        float b0 = 0.f, b1 = 0.f, b2 = 0.f, b3 = 0.f;
        #pragma unroll
        for (int k = 0; k < 32; ++k) {
            float4 pv = pld[k];              // broadcast read, conflict-free
            a0 = fmaf(pv.x, eA[k].x, a0);
            a1 = fmaf(pv.y, eA[k].y, a1);
            a2 = fmaf(pv.z, eA[k].z, a2);
            a3 = fmaf(pv.w, eA[k].w, a3);
            b0 = fmaf(pv.x, eB[k].x, b0);
            b1 = fmaf(pv.y, eB[k].y, b1);
            b2 = fmaf(pv.z, eB[k].z, b2);
            b3 = fmaf(pv.w, eB[k].w, b3);
        }
        float accA = (a0 + a1) + (a2 + a3);
        float accB = (b0 + b1) + (b2 + b3);

        float mt = mk_lds[t];
        float updA = hA0 + S + __logf(accA);
        float updB = hB0 + S + __logf(accB);
        scoreA = mt * updA + (1.f - mt) * scoreA;
        scoreB = mt * updB + (1.f - mt) * scoreB;

        float Sn = __shfl(scoreA, 0, 64) + SHIFT;

        // rotate h pipeline, issue load for t+3 (stays outstanding across steps)
        hA0 = hA1; hB0 = hB1; hA1 = hA2; hB1 = hB2;
        int tp = (t + 3 < Tt) ? (t + 3) : (Tt - 1);
        hA2 = hb[tp * Ll + jA];
        hB2 = hb[tp * Ll + jB];

        float pA = __expf(scoreA - Sn);
        float pB = __expf(scoreB - Sn);
        S = Sn;
        p_lds[jA] = pA;    // ordered after this iter's reads by alias analysis
        p_lds[jB] = pB;
    }

    // ---- final logsumexp over score + end_trans (in-wave) ----
    float vA = scoreA + end_trans[jA];
    float vB = scoreB + end_trans[jB];
    float m = fmaxf(vA, vB);
    #pragma unroll
    for (int off = 32; off; off >>= 1) m = fmaxf(m, __shfl_xor(m, off, 64));
    float e = __expf(vA - m) + __expf(vB - m);
    #pragma unroll
    for (int off = 32; off; off >>= 1) e += __shfl_xor(e, off, 64);
    if (lane == 0) out[b] = num_in[b] - (m + __logf(e));
}

extern "C" void kernel_launch(void* const* d_in, const int* in_sizes, int n_in,
                              void* d_out, int out_size, void* d_ws, size_t ws_size,
                              hipStream_t stream) {
    const float* h           = (const float*)d_in[0];
    const int*   labels      = (const int*)d_in[1];
    const float* mask        = (const float*)d_in[2];
    const float* trans       = (const float*)d_in[3];
    const float* start_trans = (const float*)d_in[4];
    const float* end_trans   = (const float*)d_in[5];
    float* out    = (float*)d_out;
    float* num_ws = (float*)d_ws;                 // [0, 256)         num results
    float* expT   = (float*)d_ws + 256;           // [256, 256+16384) exp(trans)^T

    crf_expT_kernel<<<(Ll * Ll + 255) / 256, 256, 0, stream>>>(trans, expT);
    crf_num_kernel<<<Bb, 256, 0, stream>>>(h, labels, mask, trans, start_trans, end_trans, num_ws);
    crf_den_kernel<<<Bb, 64, 0, stream>>>(h, mask, expT, start_trans, end_trans, num_ws, out);
}

// Round 6
// 580.073 us; speedup vs baseline: 3.2394x; 3.2394x over previous
//
#include <hip/hip_runtime.h>
#include <math.h>

#define Bb 256
#define Tt 1024
#define Ll 128

// ---------------- exp(trans) transpose precompute ----------------
// expT[j*128 + i] = exp(trans[i*128 + j])
__global__ __launch_bounds__(256) void crf_expT_kernel(
    const float* __restrict__ trans, float* __restrict__ expT)
{
    int idx = blockIdx.x * 256 + threadIdx.x;   // idx = j*128 + i
    if (idx < Ll * Ll) {
        int jj = idx >> 7;
        int ii = idx & (Ll - 1);
        expT[idx] = __expf(trans[ii * Ll + jj]);
    }
}

// ---------------- numerator kernel ----------------
__global__ __launch_bounds__(256) void crf_num_kernel(
    const float* __restrict__ h, const int* __restrict__ labels,
    const float* __restrict__ mask, const float* __restrict__ trans,
    const float* __restrict__ start_trans, const float* __restrict__ end_trans,
    float* __restrict__ num_out)
{
    const int b = blockIdx.x;
    const int tid = threadIdx.x;
    const int* lab = labels + b * Tt;
    const float* mk = mask + b * Tt;
    const float* hb = h + (size_t)b * Tt * Ll;

    float acc = 0.f;
    float msum = 0.f;
    for (int t = tid; t < Tt; t += 256) {
        int lt = lab[t];
        float mt = mk[t];
        msum += mt;
        if (t < Tt - 1) {
            int lt1 = lab[t + 1];
            acc += hb[t * Ll + lt] * mt + trans[lt * Ll + lt1] * mk[t + 1];
        }
    }
    for (int off = 32; off; off >>= 1) {
        acc  += __shfl_down(acc, off, 64);
        msum += __shfl_down(msum, off, 64);
    }
    __shared__ float racc[4], rmsum[4];
    const int wave = tid >> 6;
    if ((tid & 63) == 0) { racc[wave] = acc; rmsum[wave] = msum; }
    __syncthreads();
    if (tid == 0) {
        float a = racc[0] + racc[1] + racc[2] + racc[3];
        float m = rmsum[0] + rmsum[1] + rmsum[2] + rmsum[3];
        int last_idx = (int)(m + 0.5f) - 1;
        if (last_idx < 0) last_idx = 0;
        if (last_idx > Tt - 1) last_idx = Tt - 1;
        int last_lab = lab[last_idx];
        float num = a + start_trans[lab[0]];
        num += hb[(Tt - 1) * Ll + last_lab] * mk[Tt - 1];
        num += end_trans[last_lab];
        num_out[b] = num;
    }
}

// ---------------- denominator (forward scan) kernel ----------------
// 256 blocks (one per batch) x 256 threads (4 waves). R2-proven layout:
// wave w owns columns [32w,32w+32); lane pair (2c,2c+1) owns column j with
// i-split [0,64)/[64,128); et fragment = 16 named float4 (64 VGPR), resident
// under waves_per_eu(1,2) (R4-verified: VGPR=88).
//
// KEY CHANGE vs rounds 1-4: the per-step barrier is a raw
//   s_waitcnt lgkmcnt(0); s_barrier
// (one memory-clobbered asm), NOT __syncthreads(). __syncthreads emits
// s_waitcnt vmcnt(0) before s_barrier, draining the h prefetch every step
// (~1450-1700 cy/step in R1-R4). LDS-only sync keeps the 3-deep h-prefetch
// global loads in flight across steps; the compiler's counted vmcnt before
// the USE of hc (issued 3 steps earlier) is then already satisfied.
// p double-buffered (read buf[cur], write buf[cur^1] -> single barrier/step
// is race-free); shift scalars triple-buffered (slot t%3 written at t, slots
// (t+1)%3,(t+2)%3 read at t were written at t-2,t-1 -> before last barrier).
__global__ __launch_bounds__(256)
__attribute__((amdgpu_waves_per_eu(1, 2)))
void crf_den_kernel(
    const float* __restrict__ h, const float* __restrict__ mask,
    const float* __restrict__ expT, const float* __restrict__ start_trans,
    const float* __restrict__ end_trans, const float* __restrict__ num_in,
    float* __restrict__ out)
{
    __shared__ float p_lds[2][Ll];
    __shared__ float mk_lds[Tt];
    __shared__ float sc0[3];
    __shared__ float redm[4], reds[4];

    const int b = blockIdx.x;
    const int tid = threadIdx.x;
    const int wave = tid >> 6;
    const int lane = tid & 63;
    const int j = (wave << 5) + (lane >> 1);   // column 0..127
    const int ih = (lane & 1) << 6;            // i-range base: 0 or 64
    const float SH = 16.0f;

    const float* hb = h + (size_t)b * Tt * Ll;

    // stage mask row into LDS
    for (int t = tid; t < Tt; t += 256) mk_lds[t] = mask[b * Tt + t];

    // exp(trans) fragment: 16 named float4 = 64 VGPRs, contiguous load
    const float4* ep = (const float4*)(expT + j * Ll + ih);
    float4 e0  = ep[0],  e1  = ep[1],  e2  = ep[2],  e3  = ep[3];
    float4 e4  = ep[4],  e5  = ep[5],  e6  = ep[6],  e7  = ep[7];
    float4 e8  = ep[8],  e9  = ep[9],  e10 = ep[10], e11 = ep[11];
    float4 e12 = ep[12], e13 = ep[13], e14 = ep[14], e15 = ep[15];

    // bootstrap t = 0
    float score = start_trans[j] + hb[j];
    if (tid == 0) { sc0[0] = score; sc0[2] = score; }
    __syncthreads();
    if (!(lane & 1)) p_lds[0][j] = __expf(score - (sc0[0] + SH));
    __syncthreads();   // prologue barriers: full drain is fine (once)

    // h pipeline, 3 deep, issued AFTER the prologue barriers so the loads
    // stay outstanding across scan steps
    float hc = hb[1 * Ll + j];
    float hn = hb[2 * Ll + j];
    float hp = hb[3 * Ll + j];

    int cbuf = 0;
    for (int t = 1; t < Tt; ++t) {
        // off-critical-path reads + this step's prefetch issue (t+3)
        float mt = mk_lds[t];
        float Sback = sc0[(t + 1) % 3] + SH;  // shift inside current p (base: score_{t-2}[0])
        float Sfwd  = sc0[(t + 2) % 3] + SH;  // shift for new p        (base: score_{t-1}[0])
        int tp = (t + 3 < Tt) ? (t + 3) : (Tt - 1);
        float hq = hb[tp * Ll + j];

        // matvec: 64 FMAs over this lane's i-half, p read as broadcast float4
        const float4* pp = (const float4*)(p_lds[cbuf] + ih);
        float a0 = 0.f, a1 = 0.f, a2 = 0.f, a3 = 0.f;
#define FMA4(E, K) { float4 pv = pp[K];              \
        a0 = fmaf(pv.x, E.x, a0);                    \
        a1 = fmaf(pv.y, E.y, a1);                    \
        a2 = fmaf(pv.z, E.z, a2);                    \
        a3 = fmaf(pv.w, E.w, a3); }
        FMA4(e0, 0)   FMA4(e1, 1)   FMA4(e2, 2)   FMA4(e3, 3)
        FMA4(e4, 4)   FMA4(e5, 5)   FMA4(e6, 6)   FMA4(e7, 7)
        FMA4(e8, 8)   FMA4(e9, 9)   FMA4(e10, 10) FMA4(e11, 11)
        FMA4(e12, 12) FMA4(e13, 13) FMA4(e14, 14) FMA4(e15, 15)
#undef FMA4
        float acc = (a0 + a1) + (a2 + a3);
        acc += __shfl_xor(acc, 1, 64);   // pair-reduce: both lanes get full sum

        // combine (both lanes of pair, redundant)
        float upd = hc + Sback + __logf(acc);
        score = mt * upd + (1.f - mt) * score;
        if (tid == 0) sc0[t % 3] = score;            // issue early: next-step critical path
        if (!(lane & 1)) p_lds[cbuf ^ 1][j] = __expf(score - Sfwd);
        hc = hn; hn = hp; hp = hq;

        // LDS-only sync: own ds ops complete, then barrier. vmcnt NOT drained;
        // h prefetches remain in flight across the step boundary.
        asm volatile("s_waitcnt lgkmcnt(0)\n\ts_barrier" ::: "memory");
        cbuf ^= 1;
    }

    // ---- final logsumexp over score + end_trans ----
    float v = score + end_trans[j];
    float mval = ((lane & 1) == 0) ? v : -1e30f;
    #pragma unroll
    for (int off = 32; off; off >>= 1) mval = fmaxf(mval, __shfl_xor(mval, off, 64));
    if (lane == 0) redm[wave] = mval;
    __syncthreads();
    float M = fmaxf(fmaxf(redm[0], redm[1]), fmaxf(redm[2], redm[3]));
    float e = ((lane & 1) == 0) ? __expf(v - M) : 0.f;
    #pragma unroll
    for (int off = 32; off; off >>= 1) e += __shfl_xor(e, off, 64);
    if (lane == 0) reds[wave] = e;
    __syncthreads();
    if (tid == 0) {
        float den = M + __logf(reds[0] + reds[1] + reds[2] + reds[3]);
        out[b] = num_in[b] - den;
    }
}

extern "C" void kernel_launch(void* const* d_in, const int* in_sizes, int n_in,
                              void* d_out, int out_size, void* d_ws, size_t ws_size,
                              hipStream_t stream) {
    const float* h           = (const float*)d_in[0];
    const int*   labels      = (const int*)d_in[1];
    const float* mask        = (const float*)d_in[2];
    const float* trans       = (const float*)d_in[3];
    const float* start_trans = (const float*)d_in[4];
    const float* end_trans   = (const float*)d_in[5];
    float* out    = (float*)d_out;
    float* num_ws = (float*)d_ws;                 // [0, 256)         num results
    float* expT   = (float*)d_ws + 256;           // [256, 256+16384) exp(trans)^T

    crf_expT_kernel<<<(Ll * Ll + 255) / 256, 256, 0, stream>>>(trans, expT);
    crf_num_kernel<<<Bb, 256, 0, stream>>>(h, labels, mask, trans, start_trans, end_trans, num_ws);
    crf_den_kernel<<<Bb, 256, 0, stream>>>(h, mask, expT, start_trans, end_trans, num_ws, out);
}